// Round 1
// baseline (445.579 us; speedup 1.0000x reference)
//
#include <hip/hip_runtime.h>
#include <hip/hip_bf16.h>

// ---------------------------------------------------------------------------
// BGE-M3 style scoring: dense (CLS cosine), sparse (scatter-max vocab dot),
// colbert (maxsim).  Shapes: q_hidden [8,128,1024], p_hidden [64,512,1024].
// Out = concat(dense[8,64], sparse[8,64], colbert[8,64]) fp32.
//
// 5-dispatch pipeline:
//   1. conv_zero_tw : fp32->bf16 cast (q|p|W), token weights, zero Mbuf/normsq
//   2. canon_all    : sparse canonicalization (q + p in one grid)
//   3. gemm256<0>   : projection GEMM (+normsq) with dense+sparse tail blocks
//   4. gemm256<1>   : maxsim GEMM with fused per-col normalization + max
//   5. colbert_reduce
//
// gemm256 = 256x256 tile, BK=64, 8 waves (2Mx4N), 8-phase schedule with
// counted vmcnt(6) (learn_hip m201 template): double-buffered 128 KiB LDS,
// raw s_barrier, per-phase {ds_read subtile | stage 1 half-tile | 16 MFMA},
// setprio(1) around MFMA.  Never drains vmcnt to 0 in the main loop.
// ---------------------------------------------------------------------------

typedef __bf16 bf16x8 __attribute__((ext_vector_type(8)));
typedef float floatx4 __attribute__((ext_vector_type(4)));
typedef unsigned short ushort8v __attribute__((ext_vector_type(8)));

#define TEMP 0.02f

__device__ __forceinline__ unsigned short f2bf(float f) {
    unsigned u = __float_as_uint(f);
    unsigned r = (u + 0x7FFFu + ((u >> 16) & 1u)) >> 16;  // RNE
    return (unsigned short)r;
}
// order-preserving float<->uint encode for atomicMax on possibly-negative floats
__device__ __forceinline__ unsigned encf(float f) {
    unsigned u = __float_as_uint(f);
    return (u & 0x80000000u) ? ~u : (u | 0x80000000u);
}
__device__ __forceinline__ float decf(unsigned u) {
    return __uint_as_float((u & 0x80000000u) ? (u & 0x7FFFFFFFu) : ~u);
}

__device__ __forceinline__ void async_load16(void* lds, const void* g) {
    __builtin_amdgcn_global_load_lds(
        (__attribute__((address_space(1))) void*)g,
        (__attribute__((address_space(3))) void*)lds,
        16, 0, 0);
}

// ---------------------------------------------------------------------------
// conv_zero_tw: 2 rows per block (17408 blocks).
//  - fp32 -> bf16 cast of q_hidden / p_hidden / colbert_w into one buffer
//    (rows [0,1024)=q, [1024,33792)=p, [33792,34816)=W), ushort8 16B stores
//  - sparse token weight tw[row] = relu(dot(row, sparse_w) + sb) for hidden rows
//  - blocks [0,388) also zero Mbuf+normsq (388*256 words = 97+33 KB exactly)
// ---------------------------------------------------------------------------
__global__ void conv_zero_tw(const float* __restrict__ qh, const float* __restrict__ ph,
                             const float* __restrict__ wsrc, unsigned short* __restrict__ dst,
                             const float* __restrict__ sw, const float* __restrict__ sb,
                             float* __restrict__ tw, unsigned* __restrict__ zbase)
{
    __shared__ float red[4];
    int b = blockIdx.x, t = threadIdx.x;
    if (b < 388) zbase[b * 256 + t] = 0u;
    int r0 = b * 2;
    const float* src;
    bool do_tw = true;
    if (r0 < 1024)       { src = qh   + (size_t)r0 * 1024; }
    else if (r0 < 33792) { src = ph   + (size_t)(r0 - 1024) * 1024; }
    else                 { src = wsrc + (size_t)(r0 - 33792) * 1024; do_tw = false; }
    const float4* s4 = (const float4*)src;
    float4 a = s4[t * 2], c = s4[t * 2 + 1];   // 8 consecutive floats per thread
    ushort8v o;
    o[0] = f2bf(a.x); o[1] = f2bf(a.y); o[2] = f2bf(a.z); o[3] = f2bf(a.w);
    o[4] = f2bf(c.x); o[5] = f2bf(c.y); o[6] = f2bf(c.z); o[7] = f2bf(c.w);
    ((ushort8v*)dst)[(size_t)b * 256 + t] = o;
    if (do_tw) {
        const float4* w4 = (const float4*)sw;
        int wi = (t & 127) * 2;
        float4 wa = w4[wi], wc = w4[wi + 1];
        float acc = a.x * wa.x + a.y * wa.y + a.z * wa.z + a.w * wa.w
                  + c.x * wc.x + c.y * wc.y + c.z * wc.z + c.w * wc.w;
        #pragma unroll
        for (int s = 32; s; s >>= 1) acc += __shfl_down(acc, s, 64);
        if ((t & 63) == 0) red[t >> 6] = acc;   // waves 0,1 -> row r0; 2,3 -> r0+1
        __syncthreads();
        if (t == 0)   tw[r0]     = fmaxf(red[0] + red[1] + sb[0], 0.0f);
        if (t == 128) tw[r0 + 1] = fmaxf(red[2] + red[3] + sb[0], 0.0f);
    }
}

// ---------------------------------------------------------------------------
// canon_all: eff[row,l] = tw if token l is the unique argmax for its id in the
// row (ties -> lowest index) and id not in {0,1,2,3}.  One grid for q and p:
// blocks [0,8) = q rows (L=128); blocks [8,136) = p rows x 2 chunks (L=512).
// ---------------------------------------------------------------------------
__global__ void canon_all(const int* __restrict__ q_ids, const int* __restrict__ p_ids,
                          const float* __restrict__ tw,
                          float* __restrict__ eff_q, float* __restrict__ eff_p)
{
    __shared__ int   sid[512];
    __shared__ float stw[512];
    int b = blockIdx.x, t = threadIdx.x;
    const int* ids; const float* twr; float* eff; int L, chunk;
    if (b < 8) {
        L = 128; chunk = 0;
        ids = q_ids + b * 128; twr = tw + b * 128; eff = eff_q + b * 128;
    } else {
        int pr = (b - 8) >> 1; chunk = (b - 8) & 1; L = 512;
        ids = p_ids + pr * 512; twr = tw + 1024 + pr * 512; eff = eff_p + pr * 512;
    }
    for (int l = t; l < L; l += 256) { sid[l] = ids[l]; stw[l] = twr[l]; }
    __syncthreads();
    int l = chunk * 256 + t;
    if (l < L) {
        int id = sid[l];
        float wv = stw[l];
        bool kill = (id < 4);  // UNUSED ids {0,1,2,3} -> zero
        #pragma unroll 8
        for (int m = 0; m < L; ++m) {
            int idm = sid[m];
            float wm = stw[m];
            bool beats = (idm == id) & (m != l) & ((wm > wv) | ((wm == wv) & (m < l)));
            kill = kill | beats;
        }
        eff[l] = kill ? 0.0f : wv;
    }
}

// ---------------------------------------------------------------------------
// gemm256: 256x256xK bf16 MFMA GEMM, B^T layout:  C[m,n] = sum_k A[m,k]*B[n,k]
// 512 thr = 8 waves (2M x 4N), each wave owns a 128x64 output panel
// (acc[8][4] of 16x16 fragments).  BK=64, K-tile split into kh0/kh1 halves.
//
// LDS 128 KiB: smA[2][16384], smB[2][16384]; buffer d layout (elems):
//   kh*8192 + row*32 + chunkslot*8, chunkslot holds global chunk
//   slot^((row>>1)&3)  (XOR swizzle carried over from verified 128^2 kernel,
//   0 bank conflicts; global src pre-swizzled so gload_lds dest stays linear).
//
// Half-tiles H(t,0)=A-kh0 H(t,1)=B-kh0 H(t,2)=A-kh1 H(t,3)=B-kh1 (16 KB each,
// 2 gload_lds/thread).  Read schedule per tile t (4 phases):
//   P1: A f0-3 kh0 + B kh0 (8 ds_read)   -> consumes: B-kh0 last read here
//   P2: A f4-7 kh0 (4 ds_read, B reused) -> A-kh0 fully read after P2
//   P3: A f0-3 kh1 + B kh1 (8)           -> B-kh1 last read here
//   P4: A f4-7 kh1 (4)                   -> A-kh1 fully read after P4
// Stage schedule (region frees exactly one phase before each stage):
//   P1: H(t+1,2)->buf^1   P2: H(t+2,1)->buf   P3: H(t+2,0)->buf   P4: H(t+2,3)->buf
// vmcnt(6) once per tile at P4: leaves newest 3 half-tiles in flight,
// guarantees all of tile t+1 has landed before its P1 reads.
//
// MODE 0 (projection): C_bf16 = result + bias[n]; atomicAdd normsq[row].
//   grid (132+128, 4): x<132 row tiles, x>=132 tail blocks -> dense+sparse.
// MODE 1 (maxsim): scale col j by pfac, exclude CLS cols (col%512==0),
//   row-max -> atomicMax Mbuf[row*64+pb].  grid (128 colTiles, 4 rowTiles).
// ---------------------------------------------------------------------------
template<int MODE>
__global__ __launch_bounds__(512, 2)
void gemm256(const unsigned short* __restrict__ A,
             const unsigned short* __restrict__ B,
             const float* __restrict__ bias,
             unsigned short* __restrict__ C,
             unsigned* __restrict__ Mbuf,
             float* __restrict__ normsq,
             const float* __restrict__ p_mask,
             int mTiles, int N, int K,
             // tail-block (dense+sparse) inputs, MODE 0 only:
             const float* __restrict__ qh, const float* __restrict__ ph,
             const int* __restrict__ q_ids, const int* __restrict__ p_ids,
             const float* __restrict__ eff_q, const float* __restrict__ eff_p,
             float* __restrict__ out)
{
    __shared__ unsigned short smA[2][16384];
    __shared__ unsigned short smB[2][16384];
    const int tid = threadIdx.x;

    if (MODE == 0 && (int)blockIdx.x >= mTiles) {
        // ---- dense + sparse tail block (512 threads) ----
        int pair = ((int)blockIdx.x - mTiles) * 4 + (int)blockIdx.y;  // [0,512)
        int qb = pair >> 6, pb = pair & 63;
        char* lds = (char*)&smA[0][0];
        int*   qid = (int*)lds;                 // 512 B
        float* qef = (float*)(lds + 512);       // 512 B
        int*   pid = (int*)(lds + 1024);        // 2 KB
        float* pef = (float*)(lds + 3072);      // 2 KB
        float* redD = (float*)(lds + 5120);     // 24 floats
        float* redS = (float*)(lds + 5248);     // 8 floats
        int t = tid;
        if (t < 128) { qid[t] = q_ids[qb * 128 + t]; qef[t] = eff_q[qb * 128 + t]; }
        pid[t] = p_ids[pb * 512 + t]; pef[t] = eff_p[pb * 512 + t];
        // dense partial (CLS rows), float2 x 512 threads = 1024 floats
        const float2* q2 = (const float2*)(qh + (size_t)qb * 128 * 1024);
        const float2* p2 = (const float2*)(ph + (size_t)pb * 512 * 1024);
        float2 a = q2[t], b = p2[t];
        float dot = a.x * b.x + a.y * b.y;
        float nq  = a.x * a.x + a.y * a.y;
        float np  = b.x * b.x + b.y * b.y;
        #pragma unroll
        for (int sh = 32; sh; sh >>= 1) {
            dot += __shfl_down(dot, sh, 64);
            nq  += __shfl_down(nq, sh, 64);
            np  += __shfl_down(np, sh, 64);
        }
        if ((t & 63) == 0) { int wv = t >> 6; redD[wv] = dot; redD[8 + wv] = nq; redD[16 + wv] = np; }
        __syncthreads();
        if (t == 0) {
            float d = 0.0f, n1 = 0.0f, n2 = 0.0f;
            #pragma unroll
            for (int wv = 0; wv < 8; ++wv) { d += redD[wv]; n1 += redD[8 + wv]; n2 += redD[16 + wv]; }
            out[qb * 64 + pb] = d / (fmaxf(sqrtf(n1), 1e-12f) * fmaxf(sqrtf(n2), 1e-12f)) / TEMP;
        }
        // sparse: sum over matching ids
        float s = 0.0f;
        for (int idx = t; idx < 128 * 512; idx += 512) {
            int l = idx >> 9, m = idx & 511;
            if (qid[l] == pid[m]) s += qef[l] * pef[m];
        }
        #pragma unroll
        for (int sh = 32; sh; sh >>= 1) s += __shfl_down(s, sh, 64);
        if ((t & 63) == 0) redS[t >> 6] = s;
        __syncthreads();
        if (t == 0) {
            float sv = 0.0f;
            #pragma unroll
            for (int wv = 0; wv < 8; ++wv) sv += redS[wv];
            out[512 + qb * 64 + pb] = sv / TEMP;
        }
        return;
    }

    const int lane = tid & 63;
    const int w    = tid >> 6;            // wave 0..7
    const int wm   = w >> 2, wn = w & 3;  // 2 x 4 wave grid
    const int quad = lane >> 4, m16 = lane & 15;
    const int wm8 = wm * 8, wn4 = wn * 4;
    const int rowTile = (MODE == 0) ? (int)blockIdx.x : (int)blockIdx.y;
    const int colTile = (MODE == 0) ? (int)blockIdx.y : (int)blockIdx.x;
    const long long rowBase = (long long)rowTile * 256;
    const long long colBase = (long long)colTile * 256;

    // staging lane decomposition (XOR swizzle, verified conflict-free)
    const int sr  = lane >> 2;                       // row 0..15 within 16-row slab
    const int scg = (lane & 3) ^ ((lane >> 3) & 3);  // pre-swizzled global chunk
    const unsigned short* aG = A + (rowBase + w * 16 + sr) * K + scg * 8;
    const unsigned short* bG = B + (colBase + w * 16 + sr) * K + scg * 8;

    const int fragOff = m16 * 32 + (quad ^ ((m16 >> 1) & 3)) * 8;
    const int NT = K >> 6;   // 16

    floatx4 acc[8][4] = {};
    bf16x8 af[4], bkeep[4];

#define STAGE_A(d, kh, ts) do { \
    async_load16(&smA[d][(kh) * 8192 + w * 512],       aG + (long long)(ts) * 64 + (kh) * 32); \
    async_load16(&smA[d][(kh) * 8192 + (8 + w) * 512], aG + 128LL * K + (long long)(ts) * 64 + (kh) * 32); \
} while (0)
#define STAGE_B(d, kh, ts) do { \
    async_load16(&smB[d][(kh) * 8192 + w * 512],       bG + (long long)(ts) * 64 + (kh) * 32); \
    async_load16(&smB[d][(kh) * 8192 + (8 + w) * 512], bG + 128LL * K + (long long)(ts) * 64 + (kh) * 32); \
} while (0)
#define DS_A(d, kh, g) (*(const bf16x8*)&smA[d][(kh) * 8192 + (g) * 512 + fragOff])
#define DS_B(d, kh, g) (*(const bf16x8*)&smB[d][(kh) * 8192 + (g) * 512 + fragOff])
#define MFMA16(fb) \
    _Pragma("unroll") \
    for (int f_ = 0; f_ < 4; ++f_) { \
        _Pragma("unroll") \
        for (int j_ = 0; j_ < 4; ++j_) \
            acc[(fb) + f_][j_] = __builtin_amdgcn_mfma_f32_16x16x32_bf16(af[f_], bkeep[j_], acc[(fb) + f_][j_], 0, 0, 0); \
    }
#define BAR()   __builtin_amdgcn_s_barrier()
#define LGKM0() asm volatile("s_waitcnt lgkmcnt(0)" ::: "memory")

#define TILE(d, T1A, T2) do { \
    /* P1: kh0 f0-3 x B-kh0; stage H(t+1,2)=A-kh1 -> other buffer */ \
    _Pragma("unroll") for (int j_ = 0; j_ < 4; ++j_) bkeep[j_] = DS_B(d, 0, wn4 + j_); \
    _Pragma("unroll") for (int f_ = 0; f_ < 4; ++f_) af[f_]    = DS_A(d, 0, wm8 + f_); \
    STAGE_A((d) ^ 1, 1, T1A); \
    BAR(); LGKM0(); \
    __builtin_amdgcn_s_setprio(1); \
    MFMA16(0); \
    __builtin_amdgcn_s_setprio(0); \
    BAR(); \
    /* P2: kh0 f4-7 (B reused); stage H(t+2,1)=B-kh0 -> this buffer */ \
    _Pragma("unroll") for (int f_ = 0; f_ < 4; ++f_) af[f_] = DS_A(d, 0, wm8 + 4 + f_); \
    STAGE_B(d, 0, T2); \
    BAR(); LGKM0(); \
    __builtin_amdgcn_s_setprio(1); \
    MFMA16(4); \
    __builtin_amdgcn_s_setprio(0); \
    BAR(); \
    /* P3: kh1 f0-3 x B-kh1; stage H(t+2,0)=A-kh0 -> this buffer */ \
    _Pragma("unroll") for (int j_ = 0; j_ < 4; ++j_) bkeep[j_] = DS_B(d, 1, wn4 + j_); \
    _Pragma("unroll") for (int f_ = 0; f_ < 4; ++f_) af[f_]    = DS_A(d, 1, wm8 + f_); \
    STAGE_A(d, 0, T2); \
    BAR(); LGKM0(); \
    __builtin_amdgcn_s_setprio(1); \
    MFMA16(0); \
    __builtin_amdgcn_s_setprio(0); \
    BAR(); \
    /* P4: kh1 f4-7; stage H(t+2,3)=B-kh1 -> this buffer; counted vmcnt */ \
    _Pragma("unroll") for (int f_ = 0; f_ < 4; ++f_) af[f_] = DS_A(d, 1, wm8 + 4 + f_); \
    STAGE_B(d, 1, T2); \
    BAR(); LGKM0(); \
    __builtin_amdgcn_s_setprio(1); \
    MFMA16(4); \
    __builtin_amdgcn_s_setprio(0); \
    asm volatile("s_waitcnt vmcnt(6)" ::: "memory"); \
    BAR(); \
} while (0)

    // prologue: tile 0 complete (8 loads) + 3 half-tiles of tile 1 (6 loads);
    // vmcnt(6) retires the oldest 8 = all of tile 0.
    STAGE_A(0, 0, 0); STAGE_B(0, 0, 0); STAGE_A(0, 1, 0); STAGE_B(0, 1, 0);
    STAGE_B(1, 0, 1); STAGE_A(1, 0, 1); STAGE_B(1, 1, 1);
    asm volatile("s_waitcnt vmcnt(6)" ::: "memory");
    BAR();

    #pragma unroll 1
    for (int tt = 0; tt < NT; tt += 2) {
        const int u2 = (tt + 2 < NT) ? tt + 2 : NT - 1;  // clamped: harmless
        const int u3 = (tt + 3 < NT) ? tt + 3 : NT - 1;  // re-reads, dead regions
        TILE(0, tt + 1, u2);
        TILE(1, u2, u3);
    }
    asm volatile("s_waitcnt vmcnt(0)" ::: "memory");   // drain before epilogue

#undef STAGE_A
#undef STAGE_B
#undef DS_A
#undef DS_B
#undef MFMA16
#undef BAR
#undef LGKM0
#undef TILE

    if (MODE == 0) {
        float bcol[4];
        #pragma unroll
        for (int j = 0; j < 4; ++j) bcol[j] = bias[colBase + wn * 64 + j * 16 + m16];
        #pragma unroll
        for (int f = 0; f < 8; ++f) {
            long long row0 = rowBase + wm * 128 + f * 16 + quad * 4;
            #pragma unroll
            for (int r = 0; r < 4; ++r) {
                float sq = 0.0f;
                #pragma unroll
                for (int j = 0; j < 4; ++j) {
                    long long col = colBase + wn * 64 + j * 16 + m16;
                    float val = acc[f][j][r] + bcol[j];
                    C[(row0 + r) * N + col] = f2bf(val);
                    sq += val * val;
                }
                #pragma unroll
                for (int s = 1; s < 16; s <<= 1) sq += __shfl_xor(sq, s, 64);
                if (m16 == 0) atomicAdd(&normsq[row0 + r], sq);
            }
        }
    } else {
        const int pb = (int)(colBase >> 9);  // 512 p-tokens per passage
        float pfac[4];
        #pragma unroll
        for (int j = 0; j < 4; ++j) {
            int colg = (int)colBase + wn * 64 + j * 16 + m16;
            float pm = p_mask[colg];
            float pn = sqrtf(normsq[1024 + colg]);
            pfac[j] = pm / fmaxf(pn * pm, 1e-12f);
        }
        #pragma unroll
        for (int f = 0; f < 8; ++f) {
            #pragma unroll
            for (int r = 0; r < 4; ++r) {
                float mx = -3.0e38f;
                #pragma unroll
                for (int j = 0; j < 4; ++j) {
                    int colg = (int)colBase + wn * 64 + j * 16 + m16;
                    float v = acc[f][j][r] * pfac[j];
                    if ((colg & 511) == 0) v = -3.0e38f;  // exclude CLS column
                    mx = fmaxf(mx, v);
                }
                #pragma unroll
                for (int s = 1; s < 16; s <<= 1) mx = fmaxf(mx, __shfl_xor(mx, s, 64));
                if (m16 == 0) {
                    int row = (int)rowBase + wm * 128 + f * 16 + quad * 4 + r;
                    atomicMax(&Mbuf[row * 64 + pb], encf(mx));
                }
            }
        }
    }
}

// ---------------------------------------------------------------------------
// colbert final reduce: out = sum_{i>=1} dec(M[i,pb])*qfac_i / msum / TEMP
// qfac_i = qm/max(||v_i||*qm, eps)  (deferred per-row normalization)
// ---------------------------------------------------------------------------
__global__ void colbert_reduce_k(const unsigned* __restrict__ Mbuf,
                                 const float* __restrict__ q_mask,
                                 const float* __restrict__ normsq,
                                 float* __restrict__ out)
{
    int pair = blockIdx.x * 4 + (threadIdx.x >> 6);
    int lane = threadIdx.x & 63;
    int qb = pair >> 6, pb = pair & 63;
    float s = 0.0f, msum = 0.0f;
    for (int i = 1 + lane; i < 128; i += 64) {
        float qm = q_mask[qb * 128 + i];
        float qn = sqrtf(normsq[qb * 128 + i]);
        float qfac = qm / fmaxf(qn * qm, 1e-12f);
        s += decf(Mbuf[(qb * 128 + i) * 64 + pb]) * qfac;
        msum += qm;
    }
    #pragma unroll
    for (int sh = 32; sh; sh >>= 1) {
        s += __shfl_down(s, sh, 64);
        msum += __shfl_down(msum, sh, 64);
    }
    if (lane == 0) out[1024 + qb * 64 + pb] = s / msum / TEMP;
}

// ---------------------------------------------------------------------------
extern "C" void kernel_launch(void* const* d_in, const int* in_sizes, int n_in,
                              void* d_out, int out_size, void* d_ws, size_t ws_size,
                              hipStream_t stream)
{
    const float* q_hidden = (const float*)d_in[0];   // [8,128,1024]
    const float* p_hidden = (const float*)d_in[1];   // [64,512,1024]
    const float* q_mask   = (const float*)d_in[2];   // [8,128]
    const float* p_mask   = (const float*)d_in[3];   // [64,512]
    const int*   q_ids    = (const int*)d_in[4];     // [8,128]
    const int*   p_ids    = (const int*)d_in[5];     // [64,512]
    const float* colbert_w = (const float*)d_in[6];  // [1024,1024]
    const float* colbert_b = (const float*)d_in[7];  // [1024]
    const float* sparse_w  = (const float*)d_in[8];  // [1024]
    const float* sparse_b  = (const float*)d_in[9];  // [1]
    float* out = (float*)d_out;                      // [3*512]

    // workspace carve-up (~135 MB). qhb|phb|Wb contiguous; qv|pv contiguous;
    // Mbuf|normsq contiguous (zeroed inside conv_zero_tw).
    char* ws = (char*)d_ws;
    size_t off = 0;
    auto carve = [&](size_t bytes) { char* p = ws + off; off += (bytes + 255) & ~(size_t)255; return p; };
    unsigned short* qhb  = (unsigned short*)carve((size_t)1024 * 1024 * 2);
    unsigned short* phb  = (unsigned short*)carve((size_t)32768 * 1024 * 2);
    unsigned short* Wb   = (unsigned short*)carve((size_t)1024 * 1024 * 2);
    unsigned short* qv   = (unsigned short*)carve((size_t)1024 * 1024 * 2);
    unsigned short* pv   = (unsigned short*)carve((size_t)32768 * 1024 * 2);
    unsigned* Mbuf  = (unsigned*)carve((size_t)1024 * 64 * 4);        // 256 KB
    float*    normsq = (float*)carve((size_t)33792 * 4);              // 132 KB (adjacent)
    float*    tw    = (float*)carve((size_t)33792 * 4);
    float*    eff_q = (float*)carve(1024 * 4);
    float*    eff_p = (float*)carve(32768 * 4);
    (void)phb; (void)Wb; (void)pv;

    // 1. fused bf16 conversion (q,p,W) + token weights + zero Mbuf/normsq
    conv_zero_tw<<<17408, 256, 0, stream>>>(q_hidden, p_hidden, colbert_w, qhb,
                                            sparse_w, sparse_b, tw, Mbuf);

    // 2. sparse canonicalization (q + p in one grid)
    canon_all<<<136, 256, 0, stream>>>(q_ids, p_ids, tw, eff_q, eff_p);

    // 3. projection GEMM over concat(q,p): 132 row tiles x 4 col tiles,
    //    + 128 tail x-tiles (512 blocks) computing dense + sparse scores
    gemm256<0><<<dim3(132 + 128, 4), 512, 0, stream>>>(
        qhb, Wb, colbert_b, qv, nullptr, normsq, nullptr, 132, 1024, 1024,
        q_hidden, p_hidden, q_ids, p_ids, eff_q, eff_p, out);

    // 4. maxsim GEMM with fused per-col normalization + max epilogue
    gemm256<1><<<dim3(128, 4), 512, 0, stream>>>(
        qv, pv, nullptr, nullptr, Mbuf, normsq, p_mask, 4, 32768, 1024,
        nullptr, nullptr, nullptr, nullptr, nullptr, nullptr, nullptr);

    // 5. colbert final reduce (needs all maxsim blocks done)
    colbert_reduce_k<<<128, 256, 0, stream>>>(Mbuf, q_mask, normsq, out);
}

// Round 2
// 404.731 us; speedup vs baseline: 1.1009x; 1.1009x over previous
//
#include <hip/hip_runtime.h>
#include <hip/hip_bf16.h>

// ---------------------------------------------------------------------------
// BGE-M3 style scoring: dense (CLS cosine), sparse (scatter-max vocab dot),
// colbert (maxsim).  Shapes: q_hidden [8,128,1024], p_hidden [64,512,1024].
// Out = concat(dense[8,64], sparse[8,64], colbert[8,64]) fp32.
//
// 5-dispatch pipeline:
//   1. conv_zero_tw : fp32->bf16 cast (q|p|W), token weights, zero Mbuf/normsq
//   2. canon_all    : sparse canonicalization (q + p in one grid)
//   3. gemm_bt<0>   : projection GEMM (+normsq) with dense+sparse tail blocks
//   4. gemm_bt<1>   : maxsim GEMM with fused per-col normalization + max
//   5. colbert_reduce
//
// R2 change vs the 410us baseline: 1-D grids with a panel-aware XCD mapping
// (id = g*64 + k*8 + s).  The 8 blocks sharing an operand panel (A row-panel
// in MODE 0, pv col-panel in MODE 1) land on the SAME XCD (same id mod 8)
// within a 64-id window -> panel is fetched into that XCD's L2 once instead
// of 8 HBM/L3 refetches.  (R1's 256^2 8-phase experiment regressed: 1 blk/CU
// killed inter-block overlap at this problem size; reverted.)
// ---------------------------------------------------------------------------

typedef __bf16 bf16x8 __attribute__((ext_vector_type(8)));
typedef float floatx4 __attribute__((ext_vector_type(4)));
typedef unsigned short ushort8v __attribute__((ext_vector_type(8)));

#define TEMP 0.02f

__device__ __forceinline__ unsigned short f2bf(float f) {
    unsigned u = __float_as_uint(f);
    unsigned r = (u + 0x7FFFu + ((u >> 16) & 1u)) >> 16;  // RNE
    return (unsigned short)r;
}
// order-preserving float<->uint encode for atomicMax on possibly-negative floats
__device__ __forceinline__ unsigned encf(float f) {
    unsigned u = __float_as_uint(f);
    return (u & 0x80000000u) ? ~u : (u | 0x80000000u);
}
__device__ __forceinline__ float decf(unsigned u) {
    return __uint_as_float((u & 0x80000000u) ? (u & 0x7FFFFFFFu) : ~u);
}

__device__ __forceinline__ void async_load16(void* lds, const void* g) {
    __builtin_amdgcn_global_load_lds(
        (__attribute__((address_space(1))) void*)g,
        (__attribute__((address_space(3))) void*)lds,
        16, 0, 0);
}

// ---------------------------------------------------------------------------
// conv_zero_tw: 2 rows per block (17408 blocks).
//  - fp32 -> bf16 cast of q_hidden / p_hidden / colbert_w into one buffer
//    (rows [0,1024)=q, [1024,33792)=p, [33792,34816)=W), ushort8 16B stores
//  - sparse token weight tw[row] = relu(dot(row, sparse_w) + sb) for hidden rows
//  - blocks [0,388) also zero Mbuf+normsq (388*256 words = 97+33 KB exactly)
// ---------------------------------------------------------------------------
__global__ void conv_zero_tw(const float* __restrict__ qh, const float* __restrict__ ph,
                             const float* __restrict__ wsrc, unsigned short* __restrict__ dst,
                             const float* __restrict__ sw, const float* __restrict__ sb,
                             float* __restrict__ tw, unsigned* __restrict__ zbase)
{
    __shared__ float red[4];
    int b = blockIdx.x, t = threadIdx.x;
    if (b < 388) zbase[b * 256 + t] = 0u;
    int r0 = b * 2;
    const float* src;
    bool do_tw = true;
    if (r0 < 1024)       { src = qh   + (size_t)r0 * 1024; }
    else if (r0 < 33792) { src = ph   + (size_t)(r0 - 1024) * 1024; }
    else                 { src = wsrc + (size_t)(r0 - 33792) * 1024; do_tw = false; }
    const float4* s4 = (const float4*)src;
    float4 a = s4[t * 2], c = s4[t * 2 + 1];   // 8 consecutive floats per thread
    ushort8v o;
    o[0] = f2bf(a.x); o[1] = f2bf(a.y); o[2] = f2bf(a.z); o[3] = f2bf(a.w);
    o[4] = f2bf(c.x); o[5] = f2bf(c.y); o[6] = f2bf(c.z); o[7] = f2bf(c.w);
    ((ushort8v*)dst)[(size_t)b * 256 + t] = o;
    if (do_tw) {
        const float4* w4 = (const float4*)sw;
        int wi = (t & 127) * 2;
        float4 wa = w4[wi], wc = w4[wi + 1];
        float acc = a.x * wa.x + a.y * wa.y + a.z * wa.z + a.w * wa.w
                  + c.x * wc.x + c.y * wc.y + c.z * wc.z + c.w * wc.w;
        #pragma unroll
        for (int s = 32; s; s >>= 1) acc += __shfl_down(acc, s, 64);
        if ((t & 63) == 0) red[t >> 6] = acc;   // waves 0,1 -> row r0; 2,3 -> r0+1
        __syncthreads();
        if (t == 0)   tw[r0]     = fmaxf(red[0] + red[1] + sb[0], 0.0f);
        if (t == 128) tw[r0 + 1] = fmaxf(red[2] + red[3] + sb[0], 0.0f);
    }
}

// ---------------------------------------------------------------------------
// canon_all: eff[row,l] = tw if token l is the unique argmax for its id in the
// row (ties -> lowest index) and id not in {0,1,2,3}.  One grid for q and p:
// blocks [0,8) = q rows (L=128); blocks [8,136) = p rows x 2 chunks (L=512).
// ---------------------------------------------------------------------------
__global__ void canon_all(const int* __restrict__ q_ids, const int* __restrict__ p_ids,
                          const float* __restrict__ tw,
                          float* __restrict__ eff_q, float* __restrict__ eff_p)
{
    __shared__ int   sid[512];
    __shared__ float stw[512];
    int b = blockIdx.x, t = threadIdx.x;
    const int* ids; const float* twr; float* eff; int L, chunk;
    if (b < 8) {
        L = 128; chunk = 0;
        ids = q_ids + b * 128; twr = tw + b * 128; eff = eff_q + b * 128;
    } else {
        int pr = (b - 8) >> 1; chunk = (b - 8) & 1; L = 512;
        ids = p_ids + pr * 512; twr = tw + 1024 + pr * 512; eff = eff_p + pr * 512;
    }
    for (int l = t; l < L; l += 256) { sid[l] = ids[l]; stw[l] = twr[l]; }
    __syncthreads();
    int l = chunk * 256 + t;
    if (l < L) {
        int id = sid[l];
        float wv = stw[l];
        bool kill = (id < 4);  // UNUSED ids {0,1,2,3} -> zero
        #pragma unroll 8
        for (int m = 0; m < L; ++m) {
            int idm = sid[m];
            float wm = stw[m];
            bool beats = (idm == id) & (m != l) & ((wm > wv) | ((wm == wv) & (m < l)));
            kill = kill | beats;
        }
        eff[l] = kill ? 0.0f : wv;
    }
}

// ---------------------------------------------------------------------------
// 128x128xK bf16 MFMA GEMM, B^T layout:  C[m,n] = sum_k A[m,k]*B[n,k]
// tile 128x128, BK=64, 256 thr (4 waves, 2x2).
// MODE 0 (projection): C_bf16 = result + bias[n]; atomicAdd normsq[row].
//         1-D grid: ids [0,2112) GEMM (264 row tiles x 8 col tiles via the
//         XCD map below); ids [2112,2624) tail blocks -> dense+sparse scores.
// MODE 1 (maxsim): scale col j by pfac_j = pm/max(||v_j||*pm,eps), exclude
//         CLS cols (col%512==0), row-max -> atomicMax Mbuf[row*64+pb].
//         1-D grid 2048: 256 col tiles x 8 row tiles via the XCD map.
//
// XCD map (id = g*64 + k*8 + s): the 8 blocks sharing one operand panel
// (same rowTile MODE 0 / same colTile MODE 1, k = 0..7) all have id%8 == s
// -> same XCD (dispatch round-robins XCD by id), ids span only 64 -> panel
// stays in that XCD's 4 MiB L2 across all 8 uses.
//
// Staging XOR swizzle (verified): lane l loads row r=l>>2, k-chunk
// c=(l&3)^((l>>3)&3); global stays 64B-segment coalesced, LDS fragment
// reads conflict-free at fragOff = (m16*4 + (quad^((m16>>1)&3)))*8.
// ---------------------------------------------------------------------------
template<int MODE>
__global__ __launch_bounds__(256, 2)
void gemm_bt(const unsigned short* __restrict__ A,
             const unsigned short* __restrict__ B,
             const float* __restrict__ bias,
             unsigned short* __restrict__ C,
             unsigned* __restrict__ Mbuf,
             float* __restrict__ normsq,
             const float* __restrict__ p_mask,
             int mTiles, int N, int K,
             // tail-block (dense+sparse) inputs, MODE 0 only:
             const float* __restrict__ qh, const float* __restrict__ ph,
             const int* __restrict__ q_ids, const int* __restrict__ p_ids,
             const float* __restrict__ eff_q, const float* __restrict__ eff_p,
             float* __restrict__ out)
{
    __shared__ unsigned short smA[128 * 64];
    __shared__ unsigned short smB[128 * 64];
    const int tid  = threadIdx.x;

    if (MODE == 0 && (int)blockIdx.x >= mTiles) {
        // ---- dense + sparse tail block ----
        int pair = (int)blockIdx.x - mTiles;    // [0,512)
        int qb = pair >> 6, pb = pair & 63;
        char* lds = (char*)smA;
        int*   qid = (int*)lds;                 // 512 B
        float* qef = (float*)(lds + 512);       // 512 B
        int*   pid = (int*)(lds + 1024);        // 2 KB
        float* pef = (float*)(lds + 3072);      // 2 KB
        float* redD = (float*)(lds + 5120);     // 12 floats
        float* redS = (float*)(lds + 5184);     // 4 floats
        int t = tid;
        if (t < 128) { qid[t] = q_ids[qb * 128 + t]; qef[t] = eff_q[qb * 128 + t]; }
        for (int m = t; m < 512; m += 256) { pid[m] = p_ids[pb * 512 + m]; pef[m] = eff_p[pb * 512 + m]; }
        // dense partial (CLS rows)
        const float4* q4 = (const float4*)(qh + (size_t)qb * 128 * 1024);
        const float4* p4 = (const float4*)(ph + (size_t)pb * 512 * 1024);
        float4 a = q4[t], b = p4[t];
        float dot = a.x * b.x + a.y * b.y + a.z * b.z + a.w * b.w;
        float nq  = a.x * a.x + a.y * a.y + a.z * a.z + a.w * a.w;
        float np  = b.x * b.x + b.y * b.y + b.z * b.z + b.w * b.w;
        #pragma unroll
        for (int sh = 32; sh; sh >>= 1) {
            dot += __shfl_down(dot, sh, 64);
            nq  += __shfl_down(nq, sh, 64);
            np  += __shfl_down(np, sh, 64);
        }
        if ((t & 63) == 0) { int w = t >> 6; redD[w] = dot; redD[4 + w] = nq; redD[8 + w] = np; }
        __syncthreads();
        if (t == 0) {
            float d = redD[0] + redD[1] + redD[2] + redD[3];
            float n1 = redD[4] + redD[5] + redD[6] + redD[7];
            float n2 = redD[8] + redD[9] + redD[10] + redD[11];
            out[qb * 64 + pb] = d / (fmaxf(sqrtf(n1), 1e-12f) * fmaxf(sqrtf(n2), 1e-12f)) / TEMP;
        }
        // sparse: sum over matching ids
        float s = 0.0f;
        for (int idx = t; idx < 128 * 512; idx += 256) {
            int l = idx >> 9, m = idx & 511;
            if (qid[l] == pid[m]) s += qef[l] * pef[m];
        }
        #pragma unroll
        for (int sh = 32; sh; sh >>= 1) s += __shfl_down(s, sh, 64);
        if ((t & 63) == 0) redS[t >> 6] = s;
        __syncthreads();
        if (t == 0) out[512 + qb * 64 + pb] = (redS[0] + redS[1] + redS[2] + redS[3]) / TEMP;
        return;
    }

    const int lane = tid & 63;
    const int w    = tid >> 6;
    const int wm   = w >> 1, wn = w & 1;
    const int quad = lane >> 4, m16 = lane & 15;

    // panel-aware XCD decomposition: id = g*64 + k*8 + s
    const int id = (int)blockIdx.x;
    const int g  = id >> 6;
    const int s8 = id & 7;
    const int k8 = (id >> 3) & 7;
    const int rowTile = (MODE == 0) ? (g * 8 + s8) : k8;
    const int colTile = (MODE == 0) ? k8 : (g * 8 + s8);
    const int rowBase = rowTile * 128;
    const int colBase = colTile * 128;

    // staging lane decomposition (XOR swizzle)
    const int sr = lane >> 2;
    const int scg = (lane & 3) ^ ((lane >> 3) & 3);
    const unsigned short* aG0 = A + (long long)(rowBase + w * 16 + sr) * K + scg * 8;
    const unsigned short* aG1 = aG0 + 64LL * K;
    const unsigned short* bG0 = B + (long long)(colBase + w * 16 + sr) * K + scg * 8;
    const unsigned short* bG1 = bG0 + 64LL * K;
    unsigned short* lA0 = smA + w * 512;          // khalf 0 at +0, khalf 1 at +4096
    unsigned short* lA1 = smA + (w + 4) * 512;
    unsigned short* lB0 = smB + w * 512;
    unsigned short* lB1 = smB + (w + 4) * 512;

    const int fragOff = (m16 * 4 + (quad ^ ((m16 >> 1) & 3))) * 8;

    floatx4 acc[4][4] = {};

    for (int k0 = 0; k0 < K; k0 += 64) {
        async_load16(lA0,        aG0 + k0);
        async_load16(lA0 + 4096, aG0 + k0 + 32);
        async_load16(lA1,        aG1 + k0);
        async_load16(lA1 + 4096, aG1 + k0 + 32);
        async_load16(lB0,        bG0 + k0);
        async_load16(lB0 + 4096, bG0 + k0 + 32);
        async_load16(lB1,        bG1 + k0);
        async_load16(lB1 + 4096, bG1 + k0 + 32);
        __syncthreads();
        #pragma unroll
        for (int h = 0; h < 2; ++h) {
            bf16x8 af[4], bfr[4];
            #pragma unroll
            for (int f = 0; f < 4; ++f) {
                af[f]  = *(const bf16x8*)(smA + h * 4096 + (wm * 4 + f) * 512 + fragOff);
                bfr[f] = *(const bf16x8*)(smB + h * 4096 + (wn * 4 + f) * 512 + fragOff);
            }
            #pragma unroll
            for (int i = 0; i < 4; ++i)
                #pragma unroll
                for (int j = 0; j < 4; ++j)
                    acc[i][j] = __builtin_amdgcn_mfma_f32_16x16x32_bf16(af[i], bfr[j], acc[i][j], 0, 0, 0);
        }
        __syncthreads();
    }

    if (MODE == 0) {
        float bcol[4];
        #pragma unroll
        for (int j = 0; j < 4; ++j) bcol[j] = bias[colBase + wn * 64 + j * 16 + m16];
        #pragma unroll
        for (int i = 0; i < 4; ++i) {
            int row0 = rowBase + wm * 64 + i * 16 + quad * 4;
            #pragma unroll
            for (int r = 0; r < 4; ++r) {
                float sq = 0.0f;
                #pragma unroll
                for (int j = 0; j < 4; ++j) {
                    int col = colBase + wn * 64 + j * 16 + m16;
                    float val = acc[i][j][r] + bcol[j];
                    C[(long long)(row0 + r) * N + col] = f2bf(val);
                    sq += val * val;
                }
                #pragma unroll
                for (int s = 1; s < 16; s <<= 1) sq += __shfl_xor(sq, s, 64);
                if (m16 == 0) atomicAdd(&normsq[row0 + r], sq);
            }
        }
    } else {
        const int pb = colBase >> 9;  // 512 p-tokens per passage
        float pfac[4];
        #pragma unroll
        for (int j = 0; j < 4; ++j) {
            int colg = colBase + wn * 64 + j * 16 + m16;
            float pm = p_mask[colg];
            float pn = sqrtf(normsq[1024 + colg]);
            pfac[j] = pm / fmaxf(pn * pm, 1e-12f);
        }
        #pragma unroll
        for (int i = 0; i < 4; ++i) {
            #pragma unroll
            for (int r = 0; r < 4; ++r) {
                float mx = -3.0e38f;
                #pragma unroll
                for (int j = 0; j < 4; ++j) {
                    int colg = colBase + wn * 64 + j * 16 + m16;
                    float v = acc[i][j][r] * pfac[j];
                    if ((colg & 511) == 0) v = -3.0e38f;  // exclude CLS column
                    mx = fmaxf(mx, v);
                }
                #pragma unroll
                for (int s = 1; s < 16; s <<= 1) mx = fmaxf(mx, __shfl_xor(mx, s, 64));
                if (m16 == 0) {
                    int row = rowBase + wm * 64 + i * 16 + quad * 4 + r;
                    atomicMax(&Mbuf[row * 64 + pb], encf(mx));
                }
            }
        }
    }
}

// ---------------------------------------------------------------------------
// colbert final reduce: out = sum_{i>=1} dec(M[i,pb])*qfac_i / msum / TEMP
// qfac_i = qm/max(||v_i||*qm, eps)  (deferred per-row normalization)
// ---------------------------------------------------------------------------
__global__ void colbert_reduce_k(const unsigned* __restrict__ Mbuf,
                                 const float* __restrict__ q_mask,
                                 const float* __restrict__ normsq,
                                 float* __restrict__ out)
{
    int pair = blockIdx.x * 4 + (threadIdx.x >> 6);
    int lane = threadIdx.x & 63;
    int qb = pair >> 6, pb = pair & 63;
    float s = 0.0f, msum = 0.0f;
    for (int i = 1 + lane; i < 128; i += 64) {
        float qm = q_mask[qb * 128 + i];
        float qn = sqrtf(normsq[qb * 128 + i]);
        float qfac = qm / fmaxf(qn * qm, 1e-12f);
        s += decf(Mbuf[(qb * 128 + i) * 64 + pb]) * qfac;
        msum += qm;
    }
    #pragma unroll
    for (int sh = 32; sh; sh >>= 1) {
        s += __shfl_down(s, sh, 64);
        msum += __shfl_down(msum, sh, 64);
    }
    if (lane == 0) out[1024 + qb * 64 + pb] = s / msum / TEMP;
}

// ---------------------------------------------------------------------------
extern "C" void kernel_launch(void* const* d_in, const int* in_sizes, int n_in,
                              void* d_out, int out_size, void* d_ws, size_t ws_size,
                              hipStream_t stream)
{
    const float* q_hidden = (const float*)d_in[0];   // [8,128,1024]
    const float* p_hidden = (const float*)d_in[1];   // [64,512,1024]
    const float* q_mask   = (const float*)d_in[2];   // [8,128]
    const float* p_mask   = (const float*)d_in[3];   // [64,512]
    const int*   q_ids    = (const int*)d_in[4];     // [8,128]
    const int*   p_ids    = (const int*)d_in[5];     // [64,512]
    const float* colbert_w = (const float*)d_in[6];  // [1024,1024]
    const float* colbert_b = (const float*)d_in[7];  // [1024]
    const float* sparse_w  = (const float*)d_in[8];  // [1024]
    const float* sparse_b  = (const float*)d_in[9];  // [1]
    float* out = (float*)d_out;                      // [3*512]

    // workspace carve-up (~135 MB). qhb|phb|Wb contiguous; qv|pv contiguous;
    // Mbuf|normsq contiguous (zeroed inside conv_zero_tw).
    char* ws = (char*)d_ws;
    size_t off = 0;
    auto carve = [&](size_t bytes) { char* p = ws + off; off += (bytes + 255) & ~(size_t)255; return p; };
    unsigned short* qhb  = (unsigned short*)carve((size_t)1024 * 1024 * 2);
    unsigned short* phb  = (unsigned short*)carve((size_t)32768 * 1024 * 2);
    unsigned short* Wb   = (unsigned short*)carve((size_t)1024 * 1024 * 2);
    unsigned short* qv   = (unsigned short*)carve((size_t)1024 * 1024 * 2);
    unsigned short* pv   = (unsigned short*)carve((size_t)32768 * 1024 * 2);
    unsigned* Mbuf  = (unsigned*)carve((size_t)1024 * 64 * 4);        // 256 KB
    float*    normsq = (float*)carve((size_t)33792 * 4);              // 132 KB (adjacent)
    float*    tw    = (float*)carve((size_t)33792 * 4);
    float*    eff_q = (float*)carve(1024 * 4);
    float*    eff_p = (float*)carve(32768 * 4);
    (void)phb; (void)Wb; (void)pv;

    // 1. fused bf16 conversion (q,p,W) + token weights + zero Mbuf/normsq
    conv_zero_tw<<<17408, 256, 0, stream>>>(q_hidden, p_hidden, colbert_w, qhb,
                                            sparse_w, sparse_b, tw, Mbuf);

    // 2. sparse canonicalization (q + p in one grid)
    canon_all<<<136, 256, 0, stream>>>(q_ids, p_ids, tw, eff_q, eff_p);

    // 3. projection GEMM over concat(q,p): 2112 GEMM blocks (264 row x 8 col,
    //    XCD-mapped) + 512 tail blocks computing dense + sparse scores
    gemm_bt<0><<<2112 + 512, 256, 0, stream>>>(
        qhb, Wb, colbert_b, qv, nullptr, normsq, nullptr, 2112, 1024, 1024,
        q_hidden, p_hidden, q_ids, p_ids, eff_q, eff_p, out);

    // 4. maxsim GEMM with fused per-col normalization + max epilogue
    //    (2048 blocks: 256 col x 8 row, XCD-mapped)
    gemm_bt<1><<<2048, 256, 0, stream>>>(
        qv, pv, nullptr, nullptr, Mbuf, normsq, p_mask, 0, 32768, 1024,
        nullptr, nullptr, nullptr, nullptr, nullptr, nullptr, nullptr);

    // 5. colbert final reduce (needs all maxsim blocks done)
    colbert_reduce_k<<<128, 256, 0, stream>>>(Mbuf, q_mask, normsq, out);
}